// Round 5
// baseline (398.241 us; speedup 1.0000x reference)
//
#include <hip/hip_runtime.h>

#define NN 100000
#define NE 1600000
#define FIN 256
#define FH 64
#define FC 16

#define NPB 512                     // nodes per bucket
#define NBKT ((NN + NPB - 1) / NPB) // 196
#define NBLK 256                    // edge-pass blocks
#define CHUNK (NE / NBLK)           // 6250 edges/block
#define CAP 12288                   // LDS stash cap (mean 8163, +45 sigma)
#define NB_GEMM1 ((NN + 127) / 128) // 782

typedef int v2i __attribute__((ext_vector_type(2)));
typedef int v4i __attribute__((ext_vector_type(4)));
typedef short s16x8 __attribute__((ext_vector_type(8)));   // 8 bf16
typedef float f32x4 __attribute__((ext_vector_type(4)));   // MFMA acc

__device__ __forceinline__ float4 fma4(float4 v, float w, float4 a) {
    a.x = fmaf(v.x, w, a.x); a.y = fmaf(v.y, w, a.y);
    a.z = fmaf(v.z, w, a.z); a.w = fmaf(v.w, w, a.w);
    return a;
}
__device__ __forceinline__ float4 add4(float4 a, float4 v) {
    a.x += v.x; a.y += v.y; a.z += v.z; a.w += v.w;
    return a;
}
__device__ __forceinline__ float4 xor_add4(float4 r, int m) {
    r.x += __shfl_xor(r.x, m, 64); r.y += __shfl_xor(r.y, m, 64);
    r.z += __shfl_xor(r.z, m, 64); r.w += __shfl_xor(r.w, m, 64);
    return r;
}

// RNE fp32 -> bf16
__device__ __forceinline__ unsigned short bf16rne(float f) {
    unsigned u = __float_as_uint(f);
    u += 0x7FFFu + ((u >> 16) & 1u);
    return (unsigned short)(u >> 16);
}
__device__ __forceinline__ void split8(const float* f, s16x8& hi, s16x8& lo) {
    #pragma unroll
    for (int i = 0; i < 8; i++) {
        unsigned u = __float_as_uint(f[i]);
        unsigned short h = (unsigned short)((u + 0x7FFFu + ((u >> 16) & 1u)) >> 16);
        float l = f[i] - __uint_as_float((unsigned)h << 16);
        unsigned ul = __float_as_uint(l);
        hi[i] = (short)h;
        lo[i] = (short)((ul + 0x7FFFu + ((ul >> 16) & 1u)) >> 16);
    }
}

// ---- PREP: W1 -> MFMA B-frag layout (bf16 hi/lo) + int64 detect ------------
__global__ __launch_bounds__(256) void prep_k(const int* __restrict__ ei,
                                              int* __restrict__ flag,
                                              const float* __restrict__ W,
                                              unsigned short* __restrict__ Whi,
                                              unsigned short* __restrict__ Wlo) {
    int b = blockIdx.x;
    if (b == 8) {
        if (threadIdx.x == 0) {
            int z = (ei[1] == 0) & (ei[3] == 0) & (ei[5] == 0) & (ei[7] == 0);
            *flag = z;   // 1 => int64 layout, 0 => int32 layout
        }
        return;
    }
    int slot = b * 256 + threadIdx.x;      // (s,c,l)
    int l = slot & 63;
    int c = (slot >> 6) & 3;
    int s = slot >> 8;
    int k0 = s * 32 + (l >> 4) * 8;
    int col = c * 16 + (l & 15);
    #pragma unroll
    for (int i = 0; i < 8; i++) {
        float f = W[(k0 + i) * FH + col];
        unsigned short h = bf16rne(f);
        float lres = f - __uint_as_float((unsigned)h << 16);
        Whi[slot * 8 + i] = h;
        Wlo[slot * 8 + i] = bf16rne(lres);
    }
}

// ---- GEMM1 (standalone): h1 = x @ W1, 128-row MFMA tile, bf16 hi/lo --------
__global__ __launch_bounds__(256, 4) void gemm1_k(const float* __restrict__ x,
                                                  const unsigned short* __restrict__ Whi,
                                                  const unsigned short* __restrict__ Wlo,
                                                  float* __restrict__ h1) {
    const int t = threadIdx.x;
    const int lane = t & 63;
    const int wid = t >> 6;
    const int mb = blockIdx.x * 128 + wid * 32;
    const int lr = lane & 15;
    const int lk = (lane >> 4) * 8;

    int ra0 = mb + lr;
    int ra1 = mb + 16 + lr;
    const float* pa0 = x + (size_t)(ra0 < NN ? ra0 : NN - 1) * FIN + lk;
    const float* pa1 = x + (size_t)(ra1 < NN ? ra1 : NN - 1) * FIN + lk;

    f32x4 acc[2][4] = {};

    for (int s = 0; s < 8; s++) {
        float fa0[8], fa1[8];
        float4 q;
        q = *(const float4*)(pa0 + s * 32);
        fa0[0] = q.x; fa0[1] = q.y; fa0[2] = q.z; fa0[3] = q.w;
        q = *(const float4*)(pa0 + s * 32 + 4);
        fa0[4] = q.x; fa0[5] = q.y; fa0[6] = q.z; fa0[7] = q.w;
        q = *(const float4*)(pa1 + s * 32);
        fa1[0] = q.x; fa1[1] = q.y; fa1[2] = q.z; fa1[3] = q.w;
        q = *(const float4*)(pa1 + s * 32 + 4);
        fa1[4] = q.x; fa1[5] = q.y; fa1[6] = q.z; fa1[7] = q.w;

        s16x8 a0h, a0l, a1h, a1l;
        split8(fa0, a0h, a0l);
        split8(fa1, a1h, a1l);

        #pragma unroll
        for (int c = 0; c < 4; c++) {
            s16x8 wh = *(const s16x8*)&Whi[((s * 4 + c) * 64 + lane) * 8];
            s16x8 wl = *(const s16x8*)&Wlo[((s * 4 + c) * 64 + lane) * 8];
            acc[0][c] = __builtin_amdgcn_mfma_f32_16x16x32_bf16(a0h, wh, acc[0][c], 0, 0, 0);
            acc[0][c] = __builtin_amdgcn_mfma_f32_16x16x32_bf16(a0l, wh, acc[0][c], 0, 0, 0);
            acc[0][c] = __builtin_amdgcn_mfma_f32_16x16x32_bf16(a0h, wl, acc[0][c], 0, 0, 0);
            acc[1][c] = __builtin_amdgcn_mfma_f32_16x16x32_bf16(a1h, wh, acc[1][c], 0, 0, 0);
            acc[1][c] = __builtin_amdgcn_mfma_f32_16x16x32_bf16(a1l, wh, acc[1][c], 0, 0, 0);
            acc[1][c] = __builtin_amdgcn_mfma_f32_16x16x32_bf16(a1h, wl, acc[1][c], 0, 0, 0);
        }
    }
    // D layout: col = lane&15, row = (lane>>4)*4 + v
    #pragma unroll
    for (int r = 0; r < 2; r++) {
        int rowb = mb + 16 * r + (lane >> 4) * 4;
        #pragma unroll
        for (int c = 0; c < 4; c++) {
            #pragma unroll
            for (int v = 0; v < 4; v++) {
                int row = rowb + v;
                if (row < NN)
                    h1[(size_t)row * FH + 16 * c + lr] = acc[r][c][v];
            }
        }
    }
}

// ---- PASS A: per-(bucket,block) histogram, LDS atomics only ----------------
__global__ __launch_bounds__(256) void hist_k(const int* __restrict__ ei,
                                              const int* __restrict__ flag,
                                              int* __restrict__ cnt) {
    __shared__ int hist[NBKT];
    const int t = threadIdx.x, blk = blockIdx.x;
    for (int j = t; j < NBKT; j += 256) hist[j] = 0;
    __syncthreads();
    int f = *flag;
    int base = blk * CHUNK;
    if (f) {
        for (int i = t; i < CHUNK; i += 256) {
            v2i p = *(const v2i*)&ei[2 * (NE + base + i)];
            atomicAdd(&hist[p.x >> 9], 1);
        }
    } else {
        for (int i = t; i < CHUNK; i += 256) {
            int d = ei[NE + base + i];
            atomicAdd(&hist[d >> 9], 1);
        }
    }
    __syncthreads();
    for (int j = t; j < NBKT; j += 256) cnt[j * NBLK + blk] = hist[j];   // [bucket][block]
}

// ---- scan: exclusive scan of cnt[196*256] (bucket-major) + bucketBase ------
__global__ __launch_bounds__(1024) void scanoff_k(int* __restrict__ cnt,
                                                  int* __restrict__ bucketBase) {
    __shared__ int s[1024];
    const int t = threadIdx.x;
    const int SEG = (NBKT * NBLK) / 1024;     // 49
    int base = t * SEG;
    int sum = 0;
    for (int i = 0; i < SEG; i++) sum += cnt[base + i];
    s[t] = sum; __syncthreads();
    for (int off = 1; off < 1024; off <<= 1) {
        int u = (t >= off) ? s[t - off] : 0;
        __syncthreads();
        s[t] += u;
        __syncthreads();
    }
    int run = s[t] - sum;                     // exclusive prefix
    for (int i = 0; i < SEG; i++) {
        int g = base + i;
        int v = cnt[g];
        cnt[g] = run;
        if ((g & (NBLK - 1)) == 0) bucketBase[g / NBLK] = run;
        run += v;
    }
    if (t == 0) bucketBase[NBKT] = NE;
}

// ---- PASS B: scatter src|dloc into pre-scanned disjoint ranges -------------
__global__ __launch_bounds__(256) void scat_k(const int* __restrict__ ei,
                                              const int* __restrict__ flag,
                                              const int* __restrict__ cnt,
                                              int* __restrict__ sorted) {
    __shared__ int offl[NBKT];
    const int t = threadIdx.x, blk = blockIdx.x;
    for (int j = t; j < NBKT; j += 256) offl[j] = cnt[j * NBLK + blk];
    __syncthreads();
    int f = *flag;
    int base = blk * CHUNK;
    if (f) {
        for (int i = t; i < CHUNK; i += 256) {
            int e = base + i;
            v2i ps = *(const v2i*)&ei[2 * e];
            v2i pd = *(const v2i*)&ei[2 * (NE + e)];
            int s = ps.x, d = pd.x;
            int pos = atomicAdd(&offl[d >> 9], 1);
            sorted[pos] = s | ((d & (NPB - 1)) << 17);
        }
    } else {
        for (int i = t; i < CHUNK; i += 256) {
            int e = base + i;
            int s = ei[e], d = ei[NE + e];
            int pos = atomicAdd(&offl[d >> 9], 1);
            sorted[pos] = s | ((d & (NPB - 1)) << 17);
        }
    }
}

// ---- per-bucket: LDS hist + scan + rank -> CSR, row_start, dinv, h1 scale --
__global__ __launch_bounds__(256) void bucket_k(const int* __restrict__ sorted,
                                                const int* __restrict__ bucketBase,
                                                int* __restrict__ csr,
                                                int* __restrict__ row_start,
                                                float* __restrict__ dinv,
                                                float* __restrict__ h1) {
    __shared__ int stash[CAP];       // 48 KB
    __shared__ int hist[NPB];
    __shared__ int startl[NPB];
    __shared__ int cursor[NPB];
    __shared__ int ss[256];
    const int t = threadIdx.x, b = blockIdx.x;
    const int nb0 = b * NPB;
    const int ncnt = (NN - nb0 < NPB) ? (NN - nb0) : NPB;
    const int ebase = bucketBase[b];
    const int ecnt = bucketBase[b + 1] - ebase;

    hist[t] = 0; hist[t + 256] = 0;
    __syncthreads();
    for (int i = t; i < ecnt; i += 256) {
        int v = sorted[ebase + i];
        if (i < CAP) stash[i] = v;
        atomicAdd(&hist[v >> 17], 1);
    }
    __syncthreads();
    // exclusive scan of hist[512] with 256 threads (pairwise)
    int a = hist[2 * t], c = hist[2 * t + 1];
    int p = a + c;
    ss[t] = p; __syncthreads();
    for (int off = 1; off < 256; off <<= 1) {
        int u = (t >= off) ? ss[t - off] : 0;
        __syncthreads();
        ss[t] += u;
        __syncthreads();
    }
    int ex = ss[t] - p;
    startl[2 * t] = ex;       startl[2 * t + 1] = ex + a;
    cursor[2 * t] = ex;       cursor[2 * t + 1] = ex + a;
    __syncthreads();
    // row_start + dinv (coalesced)
    for (int j = t; j < ncnt; j += 256) {
        row_start[nb0 + j] = ebase + startl[j];
        dinv[nb0 + j] = rsqrtf((float)(hist[j] + 1));
    }
    if (b == 0 && t == 0) row_start[NN] = NE;
    // rank + CSR write (LDS atomic return; stores land in bucket's L2 window)
    for (int i = t; i < ecnt; i += 256) {
        int v = (i < CAP) ? stash[i] : sorted[ebase + i];
        int dl = v >> 17;
        int r = atomicAdd(&cursor[dl], 1);
        csr[ebase + r] = v & 0x1FFFF;
    }
    // h1 prescale for this bucket's nodes (coalesced float4)
    for (int q = t; q < ncnt * 16; q += 256) {
        int rl = q >> 4;
        float dv = rsqrtf((float)(hist[rl] + 1));
        size_t off = (size_t)(nb0 + rl) * FH + (q & 15) * 4;
        float4 v = *(const float4*)&h1[off];
        v.x *= dv; v.y *= dv; v.z *= dv; v.w *= dv;
        *(float4*)&h1[off] = v;
    }
}

// ---- FUSED agg1 + relu + GEMM2 (h1 prescaled; h2' = dinv*h2 stored) --------
__global__ __launch_bounds__(256) void agg1g_k(const int* __restrict__ csr,
                                               const int* __restrict__ row_start,
                                               const float* __restrict__ h1,
                                               const float* __restrict__ dinv,
                                               const float* __restrict__ b1,
                                               const float* __restrict__ W2,
                                               float* __restrict__ h2) {
    __shared__ float sW2[FH * FC];
    __shared__ float sp[4][FH];
    const int t = threadIdx.x;
    #pragma unroll
    for (int i = 0; i < 4; i++) sW2[t + 256 * i] = W2[t + 256 * i];
    __syncthreads();

    int wid = t >> 6;
    int n = blockIdx.x * 4 + wid;
    int lane = t & 63;
    if (n >= NN) return;
    int sg = lane >> 4;
    int fl = lane & 15;
    int s0 = row_start[n], s1 = row_start[n + 1];
    float4 A = make_float4(0.f, 0.f, 0.f, 0.f);
    float4 B = make_float4(0.f, 0.f, 0.f, 0.f);
    float4 C = make_float4(0.f, 0.f, 0.f, 0.f);
    float4 D = make_float4(0.f, 0.f, 0.f, 0.f);
    for (int j0 = s0; j0 < s1; j0 += 64) {
        int idx = j0 + lane;
        int sl = (idx < s1) ? csr[idx] : 0;
        int cnt = s1 - j0; if (cnt > 64) cnt = 64;
        int j = 0;
        for (; j + 16 <= cnt; j += 16) {
            int eA = __shfl(sl, j + sg, 64);
            int eB = __shfl(sl, j + 4 + sg, 64);
            int eC = __shfl(sl, j + 8 + sg, 64);
            int eD = __shfl(sl, j + 12 + sg, 64);
            float4 vA = *(const float4*)&h1[eA * FH + fl * 4];
            float4 vB = *(const float4*)&h1[eB * FH + fl * 4];
            float4 vC = *(const float4*)&h1[eC * FH + fl * 4];
            float4 vD = *(const float4*)&h1[eD * FH + fl * 4];
            A = add4(A, vA); B = add4(B, vB);
            C = add4(C, vC); D = add4(D, vD);
        }
        if (j + 8 <= cnt) {
            int eA = __shfl(sl, j + sg, 64);
            int eB = __shfl(sl, j + 4 + sg, 64);
            float4 vA = *(const float4*)&h1[eA * FH + fl * 4];
            float4 vB = *(const float4*)&h1[eB * FH + fl * 4];
            A = add4(A, vA); B = add4(B, vB);
            j += 8;
        }
        if (j + 4 <= cnt) {
            int eA = __shfl(sl, j + sg, 64);
            float4 vA = *(const float4*)&h1[eA * FH + fl * 4];
            A = add4(A, vA);
            j += 4;
        }
        int rem = cnt - j;
        if (rem > 0) {
            int jj = j + (sg < rem ? sg : 0);
            int eA = __shfl(sl, jj, 64);
            float wA = (sg < rem) ? 1.f : 0.f;
            float4 vA = *(const float4*)&h1[eA * FH + fl * 4];
            A = fma4(vA, wA, A);
        }
    }
    float4 r = add4(add4(A, B), add4(C, D));
    r = xor_add4(r, 16);
    r = xor_add4(r, 32);
    float dn = dinv[n];
    if (sg == 0) {
        float4 self = *(const float4*)&h1[n * FH + fl * 4];
        float4 bq = *(const float4*)&b1[fl * 4];
        float4 p;
        p.x = fmaxf(fmaf(r.x + self.x, dn, bq.x), 0.f);
        p.y = fmaxf(fmaf(r.y + self.y, dn, bq.y), 0.f);
        p.z = fmaxf(fmaf(r.z + self.z, dn, bq.z), 0.f);
        p.w = fmaxf(fmaf(r.w + self.w, dn, bq.w), 0.f);
        *(float4*)&sp[wid][fl * 4] = p;
    }
    __builtin_amdgcn_s_waitcnt(0);
    if (lane < FC) {
        float o = 0.f;
        #pragma unroll 8
        for (int k = 0; k < FH; k++)
            o = fmaf(sp[wid][k], sW2[k * FC + lane], o);
        h2[n * FC + lane] = o * dn;
    }
}

// ---- agg layer2 (h2' prescaled) --------------------------------------------
__global__ __launch_bounds__(256) void agg2_k(const int* __restrict__ csr,
                                              const int* __restrict__ row_start,
                                              const float* __restrict__ h2,
                                              const float* __restrict__ dinv,
                                              const float* __restrict__ b2,
                                              float* __restrict__ out) {
    const int t = threadIdx.x;
    int n = blockIdx.x * 16 + (t >> 4);
    int l16 = t & 15;
    int base = t & 48;
    int q = (t >> 2) & 3;
    int c = t & 3;
    if (n >= NN) return;
    int s0 = row_start[n], s1 = row_start[n + 1];
    float4 A = make_float4(0.f, 0.f, 0.f, 0.f);
    float4 B = make_float4(0.f, 0.f, 0.f, 0.f);
    float4 C = make_float4(0.f, 0.f, 0.f, 0.f);
    float4 D = make_float4(0.f, 0.f, 0.f, 0.f);
    for (int j0 = s0; j0 < s1; j0 += 16) {
        int idx = j0 + l16;
        int sl = (idx < s1) ? csr[idx] : 0;
        int cnt = s1 - j0; if (cnt > 16) cnt = 16;
        int j = 0;
        if (j + 16 <= cnt) {
            int eA = __shfl(sl, base + j + q, 64);
            int eB = __shfl(sl, base + j + 4 + q, 64);
            int eC = __shfl(sl, base + j + 8 + q, 64);
            int eD = __shfl(sl, base + j + 12 + q, 64);
            float4 vA = *(const float4*)&h2[eA * FC + c * 4];
            float4 vB = *(const float4*)&h2[eB * FC + c * 4];
            float4 vC = *(const float4*)&h2[eC * FC + c * 4];
            float4 vD = *(const float4*)&h2[eD * FC + c * 4];
            A = add4(A, vA); B = add4(B, vB);
            C = add4(C, vC); D = add4(D, vD);
            j += 16;
        }
        if (j + 8 <= cnt) {
            int eA = __shfl(sl, base + j + q, 64);
            int eB = __shfl(sl, base + j + 4 + q, 64);
            float4 vA = *(const float4*)&h2[eA * FC + c * 4];
            float4 vB = *(const float4*)&h2[eB * FC + c * 4];
            A = add4(A, vA); B = add4(B, vB);
            j += 8;
        }
        if (j + 4 <= cnt) {
            int eA = __shfl(sl, base + j + q, 64);
            float4 vA = *(const float4*)&h2[eA * FC + c * 4];
            A = add4(A, vA);
            j += 4;
        }
        int rem = cnt - j;
        if (rem > 0) {
            int jj = base + j + (q < rem ? q : 0);
            int eA = __shfl(sl, jj, 64);
            float wA = (q < rem) ? 1.f : 0.f;
            float4 vA = *(const float4*)&h2[eA * FC + c * 4];
            A = fma4(vA, wA, A);
        }
    }
    float4 r = add4(add4(A, B), add4(C, D));
    r = xor_add4(r, 4);
    r = xor_add4(r, 8);
    if (q == 0) {
        float dn = dinv[n];
        float4 self = *(const float4*)&h2[n * FC + c * 4];
        float4 bq = *(const float4*)&b2[c * 4];
        float4 p;
        p.x = fmaf(r.x + self.x, dn, bq.x);
        p.y = fmaf(r.y + self.y, dn, bq.y);
        p.z = fmaf(r.z + self.z, dn, bq.z);
        p.w = fmaf(r.w + self.w, dn, bq.w);
        *(float4*)&out[n * FC + c * 4] = p;
    }
}

extern "C" void kernel_launch(void* const* d_in, const int* in_sizes, int n_in,
                              void* d_out, int out_size, void* d_ws, size_t ws_size,
                              hipStream_t stream) {
    const float* x  = (const float*)d_in[0];
    const int*   ei = (const int*)d_in[1];
    const float* W1 = (const float*)d_in[2];
    const float* b1 = (const float*)d_in[3];
    const float* W2 = (const float*)d_in[4];
    const float* b2 = (const float*)d_in[5];
    float* out = (float*)d_out;

    char* ws = (char*)d_ws;
    int*   row_start  = (int*)(ws + 0);                        // 400 KB + 4
    float* dinv       = (float*)(ws + 512ull * 1024);          // 400 KB
    int*   flag       = (int*)(ws + 1024ull * 1024);           // 4 B
    int*   bucketBase = (int*)(ws + 1028ull * 1024);           // 788 B
    unsigned short* Whi = (unsigned short*)(ws + 1040ull * 1024); // 32 KB
    unsigned short* Wlo = (unsigned short*)(ws + 1072ull * 1024); // 32 KB
    int*   cnt        = (int*)(ws + 1104ull * 1024);           // 200 KB
    int*   csr        = (int*)(ws + 2048ull * 1024);           // 6.4 MB [bucket..agg2]
    int*   sorted     = (int*)(ws + 9216ull * 1024);           // 6.4 MB [scat..bucket]
    float* h2         = (float*)(ws + 9216ull * 1024);         // 6.4 MB [agg1g..agg2] (aliases sorted, dead)
    float* h1         = (float*)(ws + 16384ull * 1024);        // 25.6 MB [gemm1..agg1g]

    prep_k<<<9, 256, 0, stream>>>(ei, flag, W1, Whi, Wlo);
    gemm1_k<<<NB_GEMM1, 256, 0, stream>>>(x, Whi, Wlo, h1);
    hist_k<<<NBLK, 256, 0, stream>>>(ei, flag, cnt);
    scanoff_k<<<1, 1024, 0, stream>>>(cnt, bucketBase);
    scat_k<<<NBLK, 256, 0, stream>>>(ei, flag, cnt, sorted);
    bucket_k<<<NBKT, 256, 0, stream>>>(sorted, bucketBase, csr, row_start, dinv, h1);

    agg1g_k<<<(NN + 3) / 4, 256, 0, stream>>>(csr, row_start, h1, dinv, b1, W2, h2);
    agg2_k<<<(NN + 15) / 16, 256, 0, stream>>>(csr, row_start, h2, dinv, b2, out);
}

// Round 6
// 388.440 us; speedup vs baseline: 1.0252x; 1.0252x over previous
//
#include <hip/hip_runtime.h>

#define NN 100000
#define NE 1600000
#define FIN 256
#define FH 64
#define FC 16

#define NPB 512                     // nodes per bucket
#define NBKT ((NN + NPB - 1) / NPB) // 196
#define NBLK 256                    // edge-pass blocks
#define CHUNK (NE / NBLK)           // 6250 edges/block
#define CAP 12288                   // LDS stash cap (mean 8163, huge margin)
#define NB_GEMM1 ((NN + 127) / 128) // 782

typedef int v2i __attribute__((ext_vector_type(2)));
typedef int v4i __attribute__((ext_vector_type(4)));
typedef short s16x8 __attribute__((ext_vector_type(8)));       // 8 bf16
typedef float f32x4 __attribute__((ext_vector_type(4)));       // MFMA acc
typedef _Float16 h16x8 __attribute__((ext_vector_type(8)));    // 8 fp16 (16B)
typedef _Float16 h16x4 __attribute__((ext_vector_type(4)));    // 4 fp16 (8B)

__device__ __forceinline__ float4 fma4(float4 v, float w, float4 a) {
    a.x = fmaf(v.x, w, a.x); a.y = fmaf(v.y, w, a.y);
    a.z = fmaf(v.z, w, a.z); a.w = fmaf(v.w, w, a.w);
    return a;
}
__device__ __forceinline__ float4 add4(float4 a, float4 v) {
    a.x += v.x; a.y += v.y; a.z += v.z; a.w += v.w;
    return a;
}
__device__ __forceinline__ float4 xor_add4(float4 r, int m) {
    r.x += __shfl_xor(r.x, m, 64); r.y += __shfl_xor(r.y, m, 64);
    r.z += __shfl_xor(r.z, m, 64); r.w += __shfl_xor(r.w, m, 64);
    return r;
}

// RNE fp32 -> bf16
__device__ __forceinline__ unsigned short bf16rne(float f) {
    unsigned u = __float_as_uint(f);
    u += 0x7FFFu + ((u >> 16) & 1u);
    return (unsigned short)(u >> 16);
}
__device__ __forceinline__ void split8(const float* f, s16x8& hi, s16x8& lo) {
    #pragma unroll
    for (int i = 0; i < 8; i++) {
        unsigned u = __float_as_uint(f[i]);
        unsigned short h = (unsigned short)((u + 0x7FFFu + ((u >> 16) & 1u)) >> 16);
        float l = f[i] - __uint_as_float((unsigned)h << 16);
        unsigned ul = __float_as_uint(l);
        hi[i] = (short)h;
        lo[i] = (short)((ul + 0x7FFFu + ((ul >> 16) & 1u)) >> 16);
    }
}
// int64-vs-int32 edge_index layout, detected locally (4 cached scalar loads)
__device__ __forceinline__ int is64(const int* __restrict__ ei) {
    return (ei[1] == 0) & (ei[3] == 0) & (ei[5] == 0) & (ei[7] == 0);
}

// ---- PASS A (fused): W1 frag prep (b<8) || per-(bucket,block) histogram ----
__global__ __launch_bounds__(256) void histprep_k(const int* __restrict__ ei,
                                                  const float* __restrict__ W,
                                                  unsigned short* __restrict__ Whi,
                                                  unsigned short* __restrict__ Wlo,
                                                  int* __restrict__ cnt) {
    const int b = blockIdx.x, t = threadIdx.x;
    if (b < 8) {      // W1 -> MFMA B-frag (bf16 hi/lo)
        int slot = b * 256 + t;            // (s,c,l)
        int l = slot & 63;
        int c = (slot >> 6) & 3;
        int s = slot >> 8;
        int k0 = s * 32 + (l >> 4) * 8;
        int col = c * 16 + (l & 15);
        #pragma unroll
        for (int i = 0; i < 8; i++) {
            float f = W[(k0 + i) * FH + col];
            unsigned short h = bf16rne(f);
            float lres = f - __uint_as_float((unsigned)h << 16);
            Whi[slot * 8 + i] = h;
            Wlo[slot * 8 + i] = bf16rne(lres);
        }
        return;
    }
    __shared__ int hist[NBKT];
    const int blk = b - 8;
    for (int j = t; j < NBKT; j += 256) hist[j] = 0;
    __syncthreads();
    int f = is64(ei);
    int base = blk * CHUNK;
    if (f) {
        for (int i = t; i < CHUNK; i += 256) {
            v2i p = *(const v2i*)&ei[2 * (NE + base + i)];
            atomicAdd(&hist[p.x >> 9], 1);
        }
    } else {
        for (int i = t; i < CHUNK; i += 256) {
            int d = ei[NE + base + i];
            atomicAdd(&hist[d >> 9], 1);
        }
    }
    __syncthreads();
    for (int j = t; j < NBKT; j += 256) cnt[j * NBLK + blk] = hist[j];   // [bucket][block]
}

// ---- scan: exclusive scan of cnt[196*256] (bucket-major) + bucketBase ------
__global__ __launch_bounds__(1024) void scanoff_k(int* __restrict__ cnt,
                                                  int* __restrict__ bucketBase) {
    __shared__ int s[1024];
    const int t = threadIdx.x;
    const int SEG = (NBKT * NBLK) / 1024;     // 49
    int base = t * SEG;
    int sum = 0;
    for (int i = 0; i < SEG; i++) sum += cnt[base + i];
    s[t] = sum; __syncthreads();
    for (int off = 1; off < 1024; off <<= 1) {
        int u = (t >= off) ? s[t - off] : 0;
        __syncthreads();
        s[t] += u;
        __syncthreads();
    }
    int run = s[t] - sum;                     // exclusive prefix
    for (int i = 0; i < SEG; i++) {
        int g = base + i;
        int v = cnt[g];
        cnt[g] = run;
        if ((g & (NBLK - 1)) == 0) bucketBase[g / NBLK] = run;
        run += v;
    }
    if (t == 0) bucketBase[NBKT] = NE;
}

// ---- PASS B: scatter src|dloc into pre-scanned disjoint ranges -------------
__global__ __launch_bounds__(256) void scat_k(const int* __restrict__ ei,
                                              const int* __restrict__ cnt,
                                              int* __restrict__ sorted) {
    __shared__ int offl[NBKT];
    const int t = threadIdx.x, blk = blockIdx.x;
    for (int j = t; j < NBKT; j += 256) offl[j] = cnt[j * NBLK + blk];
    __syncthreads();
    int f = is64(ei);
    int base = blk * CHUNK;
    if (f) {
        for (int i = t; i < CHUNK; i += 256) {
            int e = base + i;
            v2i ps = *(const v2i*)&ei[2 * e];
            v2i pd = *(const v2i*)&ei[2 * (NE + e)];
            int s = ps.x, d = pd.x;
            int pos = atomicAdd(&offl[d >> 9], 1);
            sorted[pos] = s | ((d & (NPB - 1)) << 17);
        }
    } else {
        for (int i = t; i < CHUNK; i += 256) {
            int e = base + i;
            int s = ei[e], d = ei[NE + e];
            int pos = atomicAdd(&offl[d >> 9], 1);
            sorted[pos] = s | ((d & (NPB - 1)) << 17);
        }
    }
}

// ---- per-bucket counting sort: CSR + row_start + dinv ----------------------
__global__ __launch_bounds__(256) void bucket_k(const int* __restrict__ sorted,
                                                const int* __restrict__ bucketBase,
                                                int* __restrict__ csr,
                                                int* __restrict__ row_start,
                                                float* __restrict__ dinv) {
    __shared__ int stash[CAP];       // 48 KB
    __shared__ int hist[NPB];
    __shared__ int startl[NPB];
    __shared__ int cursor[NPB];
    __shared__ int ss[256];
    const int t = threadIdx.x, b = blockIdx.x;
    const int nb0 = b * NPB;
    const int ncnt = (NN - nb0 < NPB) ? (NN - nb0) : NPB;
    const int ebase = bucketBase[b];
    const int ecnt = bucketBase[b + 1] - ebase;

    hist[t] = 0; hist[t + 256] = 0;
    __syncthreads();
    for (int i = t; i < ecnt; i += 256) {
        int v = sorted[ebase + i];
        if (i < CAP) stash[i] = v;
        atomicAdd(&hist[v >> 17], 1);
    }
    __syncthreads();
    // exclusive scan of hist[512] with 256 threads (pairwise)
    int a = hist[2 * t], c = hist[2 * t + 1];
    int p = a + c;
    ss[t] = p; __syncthreads();
    for (int off = 1; off < 256; off <<= 1) {
        int u = (t >= off) ? ss[t - off] : 0;
        __syncthreads();
        ss[t] += u;
        __syncthreads();
    }
    int ex = ss[t] - p;
    startl[2 * t] = ex;       startl[2 * t + 1] = ex + a;
    cursor[2 * t] = ex;       cursor[2 * t + 1] = ex + a;
    __syncthreads();
    for (int j = t; j < ncnt; j += 256) {
        row_start[nb0 + j] = ebase + startl[j];
        dinv[nb0 + j] = rsqrtf((float)(hist[j] + 1));
    }
    if (b == 0 && t == 0) row_start[NN] = NE;
    for (int i = t; i < ecnt; i += 256) {
        int v = (i < CAP) ? stash[i] : sorted[ebase + i];
        int dl = v >> 17;
        int r = atomicAdd(&cursor[dl], 1);
        csr[ebase + r] = v & 0x1FFFF;
    }
}

// ---- GEMM1: h1h = fp16(dinv[n] * (x @ W1)), 128-row MFMA tile --------------
__global__ __launch_bounds__(256, 4) void gemm1_k(const float* __restrict__ x,
                                                  const unsigned short* __restrict__ Whi,
                                                  const unsigned short* __restrict__ Wlo,
                                                  const float* __restrict__ dinv,
                                                  _Float16* __restrict__ h1h) {
    const int t = threadIdx.x;
    const int lane = t & 63;
    const int wid = t >> 6;
    const int mb = blockIdx.x * 128 + wid * 32;
    const int lr = lane & 15;
    const int lk = (lane >> 4) * 8;

    int ra0 = mb + lr;
    int ra1 = mb + 16 + lr;
    const float* pa0 = x + (size_t)(ra0 < NN ? ra0 : NN - 1) * FIN + lk;
    const float* pa1 = x + (size_t)(ra1 < NN ? ra1 : NN - 1) * FIN + lk;

    f32x4 acc[2][4] = {};

    for (int s = 0; s < 8; s++) {
        float fa0[8], fa1[8];
        float4 q;
        q = *(const float4*)(pa0 + s * 32);
        fa0[0] = q.x; fa0[1] = q.y; fa0[2] = q.z; fa0[3] = q.w;
        q = *(const float4*)(pa0 + s * 32 + 4);
        fa0[4] = q.x; fa0[5] = q.y; fa0[6] = q.z; fa0[7] = q.w;
        q = *(const float4*)(pa1 + s * 32);
        fa1[0] = q.x; fa1[1] = q.y; fa1[2] = q.z; fa1[3] = q.w;
        q = *(const float4*)(pa1 + s * 32 + 4);
        fa1[4] = q.x; fa1[5] = q.y; fa1[6] = q.z; fa1[7] = q.w;

        s16x8 a0h, a0l, a1h, a1l;
        split8(fa0, a0h, a0l);
        split8(fa1, a1h, a1l);

        #pragma unroll
        for (int c = 0; c < 4; c++) {
            s16x8 wh = *(const s16x8*)&Whi[((s * 4 + c) * 64 + lane) * 8];
            s16x8 wl = *(const s16x8*)&Wlo[((s * 4 + c) * 64 + lane) * 8];
            acc[0][c] = __builtin_amdgcn_mfma_f32_16x16x32_bf16(a0h, wh, acc[0][c], 0, 0, 0);
            acc[0][c] = __builtin_amdgcn_mfma_f32_16x16x32_bf16(a0l, wh, acc[0][c], 0, 0, 0);
            acc[0][c] = __builtin_amdgcn_mfma_f32_16x16x32_bf16(a0h, wl, acc[0][c], 0, 0, 0);
            acc[1][c] = __builtin_amdgcn_mfma_f32_16x16x32_bf16(a1h, wh, acc[1][c], 0, 0, 0);
            acc[1][c] = __builtin_amdgcn_mfma_f32_16x16x32_bf16(a1l, wh, acc[1][c], 0, 0, 0);
            acc[1][c] = __builtin_amdgcn_mfma_f32_16x16x32_bf16(a1h, wl, acc[1][c], 0, 0, 0);
        }
    }
    // D layout: col = lane&15, row = (lane>>4)*4 + v
    #pragma unroll
    for (int r = 0; r < 2; r++) {
        int rowb = mb + 16 * r + (lane >> 4) * 4;
        #pragma unroll
        for (int v = 0; v < 4; v++) {
            int row = rowb + v;
            if (row < NN) {
                float dn = dinv[row];
                #pragma unroll
                for (int c = 0; c < 4; c++)
                    h1h[(size_t)row * FH + 16 * c + lr] = (_Float16)(acc[r][c][v] * dn);
            }
        }
    }
}

// ---- FUSED agg1 + relu + GEMM2 (h1h fp16 prescaled; h2h fp16 stored) -------
// wave = node; 8 edge slots x 8 feature-octets; fp16 gathers (128B/edge).
__global__ __launch_bounds__(256) void agg1g_k(const int* __restrict__ csr,
                                               const int* __restrict__ row_start,
                                               const _Float16* __restrict__ h1h,
                                               const float* __restrict__ dinv,
                                               const float* __restrict__ b1,
                                               const float* __restrict__ W2,
                                               _Float16* __restrict__ h2h) {
    __shared__ float sW2[FH * FC];
    __shared__ float sp[4][FH];
    const int t = threadIdx.x;
    #pragma unroll
    for (int i = 0; i < 4; i++) sW2[t + 256 * i] = W2[t + 256 * i];
    __syncthreads();

    const int wid = t >> 6;
    const int n = blockIdx.x * 4 + wid;
    const int lane = t & 63;
    if (n >= NN) return;
    const int sg = lane >> 3;        // edge slot 0..7
    const int fl = lane & 7;         // feature octet 0..7
    const h16x8* hp = (const h16x8*)h1h;   // row n at hp[n*8]
    int s0 = row_start[n], s1 = row_start[n + 1];
    float aA[8] = {}, aB[8] = {};
    for (int j0 = s0; j0 < s1; j0 += 64) {
        int idx = j0 + lane;
        int sl = (idx < s1) ? csr[idx] : 0;
        int cnt = s1 - j0; if (cnt > 64) cnt = 64;
        int j = 0;
        for (; j + 16 <= cnt; j += 16) {
            int eA = __shfl(sl, j + sg, 64);
            int eB = __shfl(sl, j + 8 + sg, 64);
            h16x8 vA = hp[eA * 8 + fl];
            h16x8 vB = hp[eB * 8 + fl];
            #pragma unroll
            for (int i = 0; i < 8; i++) { aA[i] += (float)vA[i]; aB[i] += (float)vB[i]; }
        }
        if (j + 8 <= cnt) {
            int eA = __shfl(sl, j + sg, 64);
            h16x8 vA = hp[eA * 8 + fl];
            #pragma unroll
            for (int i = 0; i < 8; i++) aA[i] += (float)vA[i];
            j += 8;
        }
        int rem = cnt - j;
        if (rem > 0) {                       // 1..7 edges, mask extra slots
            int jj = j + (sg < rem ? sg : 0);
            int eA = __shfl(sl, jj, 64);
            float w = (sg < rem) ? 1.f : 0.f;
            h16x8 vA = hp[eA * 8 + fl];
            #pragma unroll
            for (int i = 0; i < 8; i++) aA[i] = fmaf(w, (float)vA[i], aA[i]);
        }
    }
    #pragma unroll
    for (int i = 0; i < 8; i++) {
        float r = aA[i] + aB[i];
        r += __shfl_xor(r, 8, 64);
        r += __shfl_xor(r, 16, 64);
        r += __shfl_xor(r, 32, 64);
        aA[i] = r;                           // all lanes: full sum for feature fl*8+i
    }
    float dn = dinv[n];
    if (sg == 0) {
        h16x8 sv = hp[n * 8 + fl];           // self (already dinv[n]-scaled)
        float4 p0, p1;
        float4 bq0 = *(const float4*)&b1[fl * 8];
        float4 bq1 = *(const float4*)&b1[fl * 8 + 4];
        p0.x = fmaxf(fmaf(aA[0] + (float)sv[0], dn, bq0.x), 0.f);
        p0.y = fmaxf(fmaf(aA[1] + (float)sv[1], dn, bq0.y), 0.f);
        p0.z = fmaxf(fmaf(aA[2] + (float)sv[2], dn, bq0.z), 0.f);
        p0.w = fmaxf(fmaf(aA[3] + (float)sv[3], dn, bq0.w), 0.f);
        p1.x = fmaxf(fmaf(aA[4] + (float)sv[4], dn, bq1.x), 0.f);
        p1.y = fmaxf(fmaf(aA[5] + (float)sv[5], dn, bq1.y), 0.f);
        p1.z = fmaxf(fmaf(aA[6] + (float)sv[6], dn, bq1.z), 0.f);
        p1.w = fmaxf(fmaf(aA[7] + (float)sv[7], dn, bq1.w), 0.f);
        *(float4*)&sp[wid][fl * 8] = p0;
        *(float4*)&sp[wid][fl * 8 + 4] = p1;
    }
    __builtin_amdgcn_s_waitcnt(0);           // drain lgkm within wave
    if (lane < FC) {
        float o = 0.f;
        #pragma unroll 8
        for (int k = 0; k < FH; k++)
            o = fmaf(sp[wid][k], sW2[k * FC + lane], o);
        h2h[n * FC + lane] = (_Float16)(o * dn);   // h2' = dinv*h2, fp16 (3.2MB)
    }
}

// ---- agg layer2 (h2h fp16 prescaled): 16-lane subgroup/node ----------------
__global__ __launch_bounds__(256) void agg2_k(const int* __restrict__ csr,
                                              const int* __restrict__ row_start,
                                              const _Float16* __restrict__ h2h,
                                              const float* __restrict__ dinv,
                                              const float* __restrict__ b2,
                                              float* __restrict__ out) {
    const int t = threadIdx.x;
    int n = blockIdx.x * 16 + (t >> 4);
    int l16 = t & 15;
    int base = t & 48;
    int q = (t >> 2) & 3;
    int c = t & 3;
    if (n >= NN) return;
    const h16x4* hp = (const h16x4*)h2h;     // row n at hp[n*4]
    int s0 = row_start[n], s1 = row_start[n + 1];
    float4 A = make_float4(0.f, 0.f, 0.f, 0.f);
    float4 B = make_float4(0.f, 0.f, 0.f, 0.f);
    float4 C = make_float4(0.f, 0.f, 0.f, 0.f);
    float4 D = make_float4(0.f, 0.f, 0.f, 0.f);
    for (int j0 = s0; j0 < s1; j0 += 16) {
        int idx = j0 + l16;
        int sl = (idx < s1) ? csr[idx] : 0;
        int cnt = s1 - j0; if (cnt > 16) cnt = 16;
        int j = 0;
        if (j + 16 <= cnt) {
            int eA = __shfl(sl, base + j + q, 64);
            int eB = __shfl(sl, base + j + 4 + q, 64);
            int eC = __shfl(sl, base + j + 8 + q, 64);
            int eD = __shfl(sl, base + j + 12 + q, 64);
            h16x4 vA = hp[eA * 4 + c];
            h16x4 vB = hp[eB * 4 + c];
            h16x4 vC = hp[eC * 4 + c];
            h16x4 vD = hp[eD * 4 + c];
            A.x += (float)vA[0]; A.y += (float)vA[1]; A.z += (float)vA[2]; A.w += (float)vA[3];
            B.x += (float)vB[0]; B.y += (float)vB[1]; B.z += (float)vB[2]; B.w += (float)vB[3];
            C.x += (float)vC[0]; C.y += (float)vC[1]; C.z += (float)vC[2]; C.w += (float)vC[3];
            D.x += (float)vD[0]; D.y += (float)vD[1]; D.z += (float)vD[2]; D.w += (float)vD[3];
            j += 16;
        }
        if (j + 8 <= cnt) {
            int eA = __shfl(sl, base + j + q, 64);
            int eB = __shfl(sl, base + j + 4 + q, 64);
            h16x4 vA = hp[eA * 4 + c];
            h16x4 vB = hp[eB * 4 + c];
            A.x += (float)vA[0]; A.y += (float)vA[1]; A.z += (float)vA[2]; A.w += (float)vA[3];
            B.x += (float)vB[0]; B.y += (float)vB[1]; B.z += (float)vB[2]; B.w += (float)vB[3];
            j += 8;
        }
        if (j + 4 <= cnt) {
            int eA = __shfl(sl, base + j + q, 64);
            h16x4 vA = hp[eA * 4 + c];
            A.x += (float)vA[0]; A.y += (float)vA[1]; A.z += (float)vA[2]; A.w += (float)vA[3];
            j += 4;
        }
        int rem = cnt - j;
        if (rem > 0) {
            int jj = base + j + (q < rem ? q : 0);
            int eA = __shfl(sl, jj, 64);
            float wA = (q < rem) ? 1.f : 0.f;
            h16x4 vA = hp[eA * 4 + c];
            float4 vf = make_float4((float)vA[0], (float)vA[1], (float)vA[2], (float)vA[3]);
            A = fma4(vf, wA, A);
        }
    }
    float4 r = add4(add4(A, B), add4(C, D));
    r = xor_add4(r, 4);
    r = xor_add4(r, 8);
    if (q == 0) {
        float dn = dinv[n];
        h16x4 sv = hp[n * 4 + c];
        float4 bq = *(const float4*)&b2[c * 4];
        float4 p;
        p.x = fmaf(r.x + (float)sv[0], dn, bq.x);
        p.y = fmaf(r.y + (float)sv[1], dn, bq.y);
        p.z = fmaf(r.z + (float)sv[2], dn, bq.z);
        p.w = fmaf(r.w + (float)sv[3], dn, bq.w);
        *(float4*)&out[n * FC + c * 4] = p;
    }
}

extern "C" void kernel_launch(void* const* d_in, const int* in_sizes, int n_in,
                              void* d_out, int out_size, void* d_ws, size_t ws_size,
                              hipStream_t stream) {
    const float* x  = (const float*)d_in[0];
    const int*   ei = (const int*)d_in[1];
    const float* W1 = (const float*)d_in[2];
    const float* b1 = (const float*)d_in[3];
    const float* W2 = (const float*)d_in[4];
    const float* b2 = (const float*)d_in[5];
    float* out = (float*)d_out;

    char* ws = (char*)d_ws;
    int*   row_start  = (int*)(ws + 0);                           // 400 KB + 4
    float* dinv       = (float*)(ws + 512ull * 1024);             // 400 KB
    int*   bucketBase = (int*)(ws + 960ull * 1024);               // 788 B
    unsigned short* Whi = (unsigned short*)(ws + 1024ull * 1024); // 32 KB
    unsigned short* Wlo = (unsigned short*)(ws + 1088ull * 1024); // 32 KB
    int*   cnt        = (int*)(ws + 1152ull * 1024);              // 200 KB
    int*   csr        = (int*)(ws + 2048ull * 1024);              // 6.4 MB [bucket..agg2]
    int*   sorted     = (int*)(ws + 9216ull * 1024);              // 6.4 MB [scat..bucket]
    _Float16* h1h     = (_Float16*)(ws + 16384ull * 1024);        // 12.8 MB [gemm1..agg1g]
    _Float16* h2h     = (_Float16*)(ws + 30720ull * 1024);        // 3.2 MB [agg1g..agg2]

    histprep_k<<<8 + NBLK, 256, 0, stream>>>(ei, W1, Whi, Wlo, cnt);
    scanoff_k<<<1, 1024, 0, stream>>>(cnt, bucketBase);
    scat_k<<<NBLK, 256, 0, stream>>>(ei, cnt, sorted);
    bucket_k<<<NBKT, 256, 0, stream>>>(sorted, bucketBase, csr, row_start, dinv);
    gemm1_k<<<NB_GEMM1, 256, 0, stream>>>(x, Whi, Wlo, dinv, h1h);
    agg1g_k<<<(NN + 3) / 4, 256, 0, stream>>>(csr, row_start, h1h, dinv, b1, W2, h2h);
    agg2_k<<<(NN + 15) / 16, 256, 0, stream>>>(csr, row_start, h2h, dinv, b2, out);
}